// Round 16
// baseline (3332.537 us; speedup 1.0000x reference)
//
#include <hip/hip_runtime.h>
#include <stdint.h>
#include <math.h>

typedef unsigned long long u64;
typedef unsigned int u32;

// ---------------- workspace layout (bytes) ----------------
static const size_t OFF_CTL   = 0;          // [0]=u64 prefix/kstar, [8]=u32 target, [12]=u32 count
static const size_t OFF_HIST  = 1024;       // 8 passes * 256 * 4 = 8 KB
static const size_t OFF_DOTS  = 1049600;    // 16384*54*4
static const size_t OFF_WCV   = 4588544;    // 589824*4  [tap][ic][oc]
static const size_t OFF_XD    = 6947840;    // 16384*256*4 (conv out f32, HWC)
static const size_t OFF_BOX   = 23725056;   // 147456*16 (float4)
static const size_t OFF_KEYS  = 26084352;   // 147456*8
static const size_t OFF_CKEY  = 27264000;   // 6144*8
static const size_t OFF_CIDX  = 27313152;   // 6144*4
static const size_t OFF_TB    = 27337728;   // 6000*16
static const size_t OFF_TSC   = 27433728;   // 6000*4
static const size_t OFF_ALIVE = 27458048;   // 128*8
static const size_t OFF_MASK  = 27459072;   // 6000*96*8 = 4608000  end ~32.1 MB

// XLA-CPU / Eigen / Cephes f32 exp (FMA form) — bit-matches the np reference.
__device__ __forceinline__ float exp_xla(float x) {
    float m = floorf(__fmaf_rn(x, 1.44269504088896341f, 0.5f));
    float r = __fmaf_rn(m, -0.693359375f, x);
    r = __fmaf_rn(m, 2.12194440e-4f, r);
    float r2 = r * r;
    float p = 1.9875691500e-4f;
    p = __fmaf_rn(p, r, 1.3981999507e-3f);
    p = __fmaf_rn(p, r, 8.3334519073e-3f);
    p = __fmaf_rn(p, r, 4.1665795894e-2f);
    p = __fmaf_rn(p, r, 1.6666665459e-1f);
    p = __fmaf_rn(p, r, 5.0000001201e-1f);
    p = __fmaf_rn(p, r2, r);
    p = __fadd_rn(p, 1.0f);
    int mi = (int)m;
    return p * __int_as_float((mi + 127) << 23);
}

// ---------------- weight prep: rpn_w [oc][ic][tap] -> f32 [tap][ic][oc] ------
__global__ void prep_wcv(const float* __restrict__ rpn_w, float* __restrict__ wcv) {
    int t = blockIdx.x * 256 + threadIdx.x;
    if (t >= 589824) return;
    int tap = t / 65536, rem = t % 65536, ic = rem / 256, oc = rem % 256;
    wcv[t] = rpn_w[oc * 2304 + ic * 9 + tap];
}

// ---------------- conv3x3: r13 shape + oc-group loop -------------------------
// Per (px,oc): ONE f32 acc, k=(tap,ic) ascending, fma(0,w,acc)==acc for pads —
// bit-exact r12 chain. Block = 16x16 px tile x 64 ocs (4 groups of 16; weights
// restaged per (tap,group) in 16KB LDS, wave-uniform broadcast reads).
// Grid (8,8,4), x-major ids => a tile's 4 oc-blocks share id%8 (same XCD L2).
__global__ __launch_bounds__(256, 1) void conv3x3(const float* __restrict__ feat,
                                                  const float* __restrict__ wcv,
                                                  const float* __restrict__ rpn_b,
                                                  float* __restrict__ xd) {
    __shared__ float sW[4096];  // [ic][16 oc] for current (tap, oc-group)
    const int tx = threadIdx.x & 15, ty = threadIdx.x >> 4;
    const int gx = blockIdx.x * 16 + tx, gy = blockIdx.y * 16 + ty;
    const int pix = gy * 128 + gx;
    for (int ocg = 0; ocg < 4; ++ocg) {
        const int oc0 = blockIdx.z * 64 + ocg * 16;
        float acc[16];
#pragma unroll
        for (int o = 0; o < 16; ++o) acc[o] = 0.f;
#pragma unroll
        for (int tap = 0; tap < 9; ++tap) {           // k-major: tap (ky,kx)
            __syncthreads();
            for (int idx = threadIdx.x; idx < 4096; idx += 256) {
                int ic = idx >> 4, oc = idx & 15;
                sW[idx] = wcv[tap * 65536 + ic * 256 + oc0 + oc];
            }
            __syncthreads();
            const int yy = gy + tap / 3 - 1, xx = gx + tap % 3 - 1;
            const bool in = (yy >= 0 && yy < 128 && xx >= 0 && xx < 128);
            const float* fp = feat + yy * 128 + xx;
            for (int ic = 0; ic < 256; ++ic) {        // k-minor: ic ascending
                float f = in ? fp[ic * 16384] : 0.f;
                const float* w = sW + ic * 16;        // uniform -> broadcast
#pragma unroll
                for (int o = 0; o < 16; ++o) acc[o] = __fmaf_rn(f, w[o], acc[o]);
            }
        }
        float* outp = xd + (size_t)pix * 256 + oc0;
#pragma unroll
        for (int o = 0; o < 16; ++o) {
            float v = __fadd_rn(acc[o], rpn_b[oc0 + o]);
            outp[o] = v > 0.f ? v : 0.f;
        }
    }
}

// ---------------- heads: 1x1 convs, k=ic sequential f32 FMA (float4 loads) ---
__global__ __launch_bounds__(256, 1) void heads_seq(const float* __restrict__ xd,
                                                    const float* __restrict__ cls_w,
                                                    const float* __restrict__ box_w,
                                                    float* __restrict__ dots) {
    __shared__ float sX[4][260];  // row stride 1040 B: 16B-aligned
    const int tid = threadIdx.x;
    const int pix0 = blockIdx.x * 4;
    for (int idx = tid; idx < 1024; idx += 256)
        sX[idx >> 8][idx & 255] = xd[(size_t)(pix0 + (idx >> 8)) * 256 + (idx & 255)];
    __syncthreads();
    if (tid < 216) {
        const int pl = tid / 54, o = tid % 54;
        const float* wr = (o < 18) ? (cls_w + o * 256) : (box_w + (o - 18) * 256);
        const float4* x4 = (const float4*)&sX[pl][0];
        const float4* w4 = (const float4*)wr;
        float acc = 0.f;
        for (int q = 0; q < 64; ++q) {                // ic = 4q..4q+3, in order
            float4 xv = x4[q];
            float4 wv = w4[q];
            acc = __fmaf_rn(xv.x, wv.x, acc);
            acc = __fmaf_rn(xv.y, wv.y, acc);
            acc = __fmaf_rn(xv.z, wv.z, acc);
            acc = __fmaf_rn(xv.w, wv.w, acc);
        }
        dots[(size_t)(pix0 + pl) * 54 + o] = acc;
    }
}

// ---------------- decode: stepwise-F32 softmax + box decode, XLA exp ---------
__global__ __launch_bounds__(256, 1) void decode(const float* __restrict__ dots,
                                                 const float* __restrict__ cls_b,
                                                 const float* __restrict__ box_b,
                                                 float4* __restrict__ boxes,
                                                 u64* __restrict__ keys) {
    const int pix = blockIdx.x * 256 + threadIdx.x;
    if (pix >= 16384) return;
    const float* dt = dots + (size_t)pix * 54;
    float d[54];
#pragma unroll
    for (int i = 0; i < 54; ++i)
        d[i] = __fadd_rn(dt[i], (i < 18 ? cls_b[i] : box_b[i - 18]));
    float m = d[0];
#pragma unroll
    for (int i = 1; i < 18; ++i) m = fmaxf(m, d[i]);
    float e[18];
#pragma unroll
    for (int i = 0; i < 18; ++i) e[i] = exp_xla(__fsub_rn(d[i], m));
    float s = e[0];
#pragma unroll
    for (int i = 1; i < 18; ++i) s = __fadd_rn(s, e[i]);
    const int y = pix >> 7, x = pix & 127;
    const float shx = (float)(x * 32), shy = (float)(y * 32);
    const float AW[9] = {368.f, 736.f, 1472.f, 256.f, 512.f, 1024.f, 176.f, 352.f, 704.f};
    const float AH[9] = {192.f, 384.f, 768.f, 256.f, 512.f, 1024.f, 352.f, 704.f, 1408.f};
#pragma unroll
    for (int a = 0; a < 9; ++a) {
        float score = e[9 + a] / s;
        float wa = AW[a], ha = AH[a];
        float cxa = __fadd_rn(shx, 7.5f), cya = __fadd_rn(shy, 7.5f);
        float dx = d[18 + 4 * a], dyy = d[19 + 4 * a];
        float dw = d[20 + 4 * a], dh = d[21 + 4 * a];
        float cx = __fadd_rn(__fmul_rn(dx, wa), cxa);
        float cy = __fadd_rn(__fmul_rn(dyy, ha), cya);
        float pw = __fmul_rn(wa, exp_xla(dw));
        float ph = __fmul_rn(ha, exp_xla(dh));
        float hx = __fmul_rn(0.5f, pw), hy = __fmul_rn(0.5f, ph);
        float x1 = fminf(fmaxf(__fsub_rn(cx, hx), 0.f), 4095.f);
        float y1 = fminf(fmaxf(__fsub_rn(cy, hy), 0.f), 4095.f);
        float x2 = fminf(fmaxf(__fadd_rn(cx, hx), 0.f), 4095.f);
        float y2 = fminf(fmaxf(__fadd_rn(cy, hy), 0.f), 4095.f);
        float vw = __fadd_rn(__fsub_rn(x2, x1), 1.0f);
        float vh = __fadd_rn(__fsub_rn(y2, y1), 1.0f);
        bool valid = (vw >= 16.0f) && (vh >= 16.0f);
        int i = pix * 9 + a;
        boxes[i] = make_float4(x1, y1, x2, y2);
        u64 k;
        if (valid) {
            u32 b = __float_as_uint(score);
            k = ((u64)(u32)~(b | 0x80000000u) << 32) | (u32)i;
        } else {
            k = (0xFFFFFFFFULL << 32) | (u32)i;
        }
        keys[i] = k;
    }
}

// ---------------- radix select: 8 passes of 8 bits, LDS histograms -----------
__global__ __launch_bounds__(256) void hist8(const u64* __restrict__ keys,
                                             u32* __restrict__ ghist,
                                             const u64* __restrict__ pfx, int pass) {
    __shared__ u32 lh[256];
    lh[threadIdx.x] = 0;
    __syncthreads();
    const u64 pref = *pfx;  // pass 0: unused (memset 0)
    const int shift = 56 - 8 * pass;
    for (int i = blockIdx.x * 256 + threadIdx.x; i < 147456; i += 64 * 256) {
        u64 k = keys[i];
        bool match = (pass == 0) || ((k >> (shift + 8)) == pref);
        if (match) atomicAdd(&lh[(u32)(k >> shift) & 0xFFu], 1u);
    }
    __syncthreads();
    if (lh[threadIdx.x]) atomicAdd(&ghist[threadIdx.x], lh[threadIdx.x]);
}

__global__ __launch_bounds__(256) void scan8(const u32* __restrict__ ghist,
                                             u64* pfx, u32* tgt, int pass) {
    __shared__ u32 h[256];
    __shared__ u32 incl[256];
    const int t = threadIdx.x;
    u32 target = (pass == 0) ? 6000u : *tgt;   // read before winner's write
    u64 p0 = (pass == 0) ? 0ULL : *pfx;
    h[t] = ghist[t];
    incl[t] = h[t];
    __syncthreads();
    for (int off = 1; off < 256; off <<= 1) {
        u32 v = (t >= off) ? incl[t - off] : 0u;
        __syncthreads();
        incl[t] += v;
        __syncthreads();
    }
    u32 before = incl[t] - h[t];
    if (before < target && target <= incl[t]) {   // unique winner
        *pfx = (p0 << 8) | (u64)t;
        *tgt = target - before;
    }
}

__global__ void compact(const u64* __restrict__ keys, const u64* __restrict__ kstar,
                        u32* count, u64* __restrict__ ckey, u32* __restrict__ cidx) {
    int i = blockIdx.x * 256 + threadIdx.x;
    if (i >= 147456) return;
    u64 k = keys[i];
    if (k <= *kstar) {  // unique keys -> exactly 6000 pass
        u32 pos = atomicAdd(count, 1u);
        if (pos < 6144) { ckey[pos] = k; cidx[pos] = (u32)(k & 0xFFFFFFFFu); }
    }
}

// ---------------- exact rank (keys unique) + gather sorted top-6000 ----------
// exactly 6000 compacted entries -> every tb/tsc slot is written (no init pass)
__global__ __launch_bounds__(256) void rank_scatter(const u64* __restrict__ ckey,
                                                    const u32* __restrict__ cidx,
                                                    const u32* __restrict__ count,
                                                    const float4* __restrict__ boxes,
                                                    float4* __restrict__ tb,
                                                    float* __restrict__ tsc) {
    __shared__ u64 LK[6144];
    int N = (int)*count; if (N > 6144) N = 6144;
    for (int i = threadIdx.x; i < N; i += 256) LK[i] = ckey[i];
    __syncthreads();
    int e = blockIdx.x * 256 + threadIdx.x;
    if (e >= N) return;
    u64 myK = LK[e];
    u32 myI = cidx[e];
    int rank = 0;
    for (int c = 0; c < N; ++c) rank += (LK[c] < myK);
    if (rank < 6000) {
        tb[rank] = boxes[myI];
        u32 hi = (u32)(myK >> 32);
        tsc[rank] = (hi == 0xFFFFFFFFu) ? -__builtin_inff()
                                        : __uint_as_float(~hi & 0x7FFFFFFFu);
    }
}

// ---------------- alive bitmask init (94 words used, 96 written) -------------
__global__ void alive_init(const float* __restrict__ tsc, u64* __restrict__ alive0) {
    int r = blockIdx.x * 256 + threadIdx.x;  // 24*256 = 6144 -> words 0..95
    bool a = false;
    if (r < 6000) a = tsc[r] > -__builtin_inff();
    u64 b = __ballot(a);
    if ((threadIdx.x & 63) == 0) alive0[r >> 6] = b;
}

// ---------------- suppression bitmask: m[j][i] = iou(tb[j],tb[i]) > 0.7 ------
__global__ __launch_bounds__(256) void nms_mask(const float4* __restrict__ tb,
                                                u64* __restrict__ mask) {
    int tid = blockIdx.x * 256 + threadIdx.x;
    if (tid >= 6000 * 94) return;
    int j = tid / 94, w = tid % 94;
    float4 bj = tb[j];
    float arJ = __fmul_rn(__fadd_rn(__fsub_rn(bj.z, bj.x), 1.0f),
                          __fadd_rn(__fsub_rn(bj.w, bj.y), 1.0f));
    u64 m = 0;
    int base = w * 64;
#pragma unroll 4
    for (int b = 0; b < 64; ++b) {
        int i = base + b;
        if (i >= 6000) break;
        float4 bi = tb[i];
        float arI = __fmul_rn(__fadd_rn(__fsub_rn(bi.z, bi.x), 1.0f),
                              __fadd_rn(__fsub_rn(bi.w, bi.y), 1.0f));
        float xx1 = fmaxf(bj.x, bi.x), yy1 = fmaxf(bj.y, bi.y);
        float xx2 = fminf(bj.z, bi.z), yy2 = fminf(bj.w, bi.w);
        float ww = fmaxf(__fadd_rn(__fsub_rn(xx2, xx1), 1.0f), 0.0f);
        float hh = fmaxf(__fadd_rn(__fsub_rn(yy2, yy1), 1.0f), 0.0f);
        float inter = __fmul_rn(ww, hh);
        float uni = __fsub_rn(__fadd_rn(arJ, arI), inter);
        float iou = inter / uni;
        if (iou > 0.7f) m |= (1ULL << b);
    }
    mask[(size_t)j * 96 + w] = m;
}

// ---------------- sequential NMS scan with 4-slot row prefetch ---------------
__global__ __launch_bounds__(64, 1) void nms_seq(const u64* __restrict__ alive0,
                                                 const u64* __restrict__ mask,
                                                 const float4* __restrict__ tb,
                                                 float* __restrict__ out) {
    const int lane = threadIdx.x;
    u64 wl = alive0[lane];                            // word lane
    u64 wh = (lane < 30) ? alive0[64 + lane] : 0ULL;  // word 64+lane
    int cj[4] = {-1, -1, -1, -1};
    u64 cl[4] = {0, 0, 0, 0}, ch[4] = {0, 0, 0, 0};
    for (int k = 0; k < 1000; ++k) {
        // ---- j = first alive ----
        int j;
        {
            u64 blo = __ballot(wl != 0ULL);
            if (blo) {
                int l = __ffsll((long long)blo) - 1;
                u64 w = __shfl(wl, l);
                j = l * 64 + __ffsll((long long)w) - 1;
            } else {
                u64 bhi = __ballot(wh != 0ULL);
                if (!bhi) break;  // exhausted: remaining out rows stay 0
                int l = __ffsll((long long)bhi) - 1;
                u64 w = __shfl(wh, l);
                j = (64 + l) * 64 + __ffsll((long long)w) - 1;
            }
        }
        if (lane == 0) {
            float4 bj = tb[j];
            out[k * 5 + 1] = bj.x;
            out[k * 5 + 2] = bj.y;
            out[k * 5 + 3] = bj.z;
            out[k * 5 + 4] = bj.w;
        }
        // ---- row j: prefetched slot or direct load ----
        u64 rl, rh;
        int s = (j == cj[0]) ? 0 : (j == cj[1]) ? 1 : (j == cj[2]) ? 2
              : (j == cj[3]) ? 3 : -1;
        if (s >= 0) {
            rl = cl[s]; rh = ch[s];
        } else {
            rl = mask[(size_t)j * 96 + lane];
            rh = (lane < 30) ? mask[(size_t)j * 96 + 64 + lane] : 0ULL;
        }
        // ---- candidates: next 4 alive strictly after j ----
        const int jw = j >> 6, jb = j & 63;
        u64 ml = wl, mh = wh;
        if (lane < jw) ml = 0;
        if (lane == jw) ml = (jb == 63) ? 0ULL : (ml & (~0ULL << (jb + 1)));
        if (64 + lane < jw) mh = 0;
        if (64 + lane == jw) mh = (jb == 63) ? 0ULL : (mh & (~0ULL << (jb + 1)));
#pragma unroll
        for (int q = 0; q < 4; ++q) {
            int c = -1;
            u64 blo = __ballot(ml != 0ULL);
            if (blo) {
                int l = __ffsll((long long)blo) - 1;
                u64 w = __shfl(ml, l);
                c = l * 64 + __ffsll((long long)w) - 1;
            } else {
                u64 bhi = __ballot(mh != 0ULL);
                if (bhi) {
                    int l = __ffsll((long long)bhi) - 1;
                    u64 w = __shfl(mh, l);
                    c = (64 + l) * 64 + __ffsll((long long)w) - 1;
                }
            }
            cj[q] = c;
            if (c >= 0) {
                int cw = c >> 6, cb = c & 63;
                if (cw < 64) { if (lane == cw) ml &= ~(1ULL << cb); }
                else         { if (lane == cw - 64) mh &= ~(1ULL << cb); }
                cl[q] = mask[(size_t)c * 96 + lane];              // prefetch
                ch[q] = (lane < 30) ? mask[(size_t)c * 96 + 64 + lane] : 0ULL;
            }
        }
        // ---- apply row j ----
        wl &= ~rl;
        if (lane < 30) wh &= ~rh;
    }
}

// ---------------- host ----------------
extern "C" void kernel_launch(void* const* d_in, const int* in_sizes, int n_in,
                              void* d_out, int out_size, void* d_ws, size_t ws_size,
                              hipStream_t stream) {
    const float *feat = nullptr, *rpn_w = nullptr, *rpn_b = nullptr;
    const float *cls_w = nullptr, *cls_b = nullptr, *box_w = nullptr, *box_b = nullptr;
    for (int i = 0; i < n_in; ++i) {
        switch (in_sizes[i]) {
            case 4194304: feat  = (const float*)d_in[i]; break;
            case 589824:  rpn_w = (const float*)d_in[i]; break;
            case 256:     rpn_b = (const float*)d_in[i]; break;
            case 4608:    cls_w = (const float*)d_in[i]; break;
            case 18:      cls_b = (const float*)d_in[i]; break;
            case 9216:    box_w = (const float*)d_in[i]; break;
            case 36:      box_b = (const float*)d_in[i]; break;
            default: break;  // image dims hardcoded (4096)
        }
    }

    char* w = (char*)d_ws;
    u64* pfx       = (u64*)(w + OFF_CTL);
    u32* tgt       = (u32*)(w + OFF_CTL + 8);
    u32* ctlCount  = (u32*)(w + OFF_CTL + 12);
    u32* hist      = (u32*)(w + OFF_HIST);
    float* dots    = (float*)(w + OFF_DOTS);
    float* wcv     = (float*)(w + OFF_WCV);
    float* xd      = (float*)(w + OFF_XD);
    float4* boxes  = (float4*)(w + OFF_BOX);
    u64* keys      = (u64*)(w + OFF_KEYS);
    u64* ckey      = (u64*)(w + OFF_CKEY);
    u32* cidx      = (u32*)(w + OFF_CIDX);
    float4* tb     = (float4*)(w + OFF_TB);
    float* tsc     = (float*)(w + OFF_TSC);
    u64* alive0    = (u64*)(w + OFF_ALIVE);
    u64* mask      = (u64*)(w + OFF_MASK);

    hipMemsetAsync(d_ws, 0, OFF_HIST + 8 * 256 * 4, stream);  // ctl + 8 hists
    hipMemsetAsync(d_out, 0, (size_t)out_size * sizeof(float), stream);

    prep_wcv<<<2304, 256, 0, stream>>>(rpn_w, wcv);
    conv3x3<<<dim3(8, 8, 4), 256, 0, stream>>>(feat, wcv, rpn_b, xd);
    heads_seq<<<4096, 256, 0, stream>>>(xd, cls_w, box_w, dots);
    decode<<<64, 256, 0, stream>>>(dots, cls_b, box_b, boxes, keys);
    for (int p = 0; p < 8; ++p) {
        hist8<<<64, 256, 0, stream>>>(keys, hist + p * 256, pfx, p);
        scan8<<<1, 256, 0, stream>>>(hist + p * 256, pfx, tgt, p);
    }
    compact<<<576, 256, 0, stream>>>(keys, pfx, ctlCount, ckey, cidx);
    rank_scatter<<<24, 256, 0, stream>>>(ckey, cidx, ctlCount, boxes, tb, tsc);
    alive_init<<<24, 256, 0, stream>>>(tsc, alive0);
    nms_mask<<<2204, 256, 0, stream>>>(tb, mask);
    nms_seq<<<1, 64, 0, stream>>>(alive0, mask, tb, (float*)d_out);
}

// Round 17
// 2155.094 us; speedup vs baseline: 1.5464x; 1.5464x over previous
//
#include <hip/hip_runtime.h>
#include <stdint.h>
#include <math.h>

typedef unsigned long long u64;
typedef unsigned int u32;
typedef float float4a __attribute__((ext_vector_type(4), aligned(4)));

// ---------------- workspace layout (bytes) ----------------
static const size_t OFF_CTL   = 0;          // [0]=u64 prefix/kstar, [8]=u32 target, [12]=u32 count
static const size_t OFF_HIST  = 1024;       // 8 passes * 256 * 4 = 8 KB
static const size_t OFF_DOTS  = 1049600;    // 16384*54*4
static const size_t OFF_WCV   = 4588544;    // 589824*4  [tap][ic][oc]
static const size_t OFF_XD    = 6947840;    // 16384*256*4 (conv out f32, HWC)
static const size_t OFF_BOX   = 23725056;   // 147456*16 (float4)
static const size_t OFF_KEYS  = 26084352;   // 147456*8
static const size_t OFF_CKEY  = 27264000;   // 6144*8
static const size_t OFF_CIDX  = 27313152;   // 6144*4
static const size_t OFF_TB    = 27337728;   // 6000*16
static const size_t OFF_TSC   = 27433728;   // 6000*4
static const size_t OFF_ALIVE = 27458048;   // 128*8
static const size_t OFF_MASK  = 27459072;   // 6000*96*8 = 4608000
static const size_t OFF_FPAD  = 32067584;   // 256*130*132*4 = 17571840  end ~49.6 MB

// XLA-CPU / Eigen / Cephes f32 exp (FMA form) — bit-matches the np reference.
__device__ __forceinline__ float exp_xla(float x) {
    float m = floorf(__fmaf_rn(x, 1.44269504088896341f, 0.5f));
    float r = __fmaf_rn(m, -0.693359375f, x);
    r = __fmaf_rn(m, 2.12194440e-4f, r);
    float r2 = r * r;
    float p = 1.9875691500e-4f;
    p = __fmaf_rn(p, r, 1.3981999507e-3f);
    p = __fmaf_rn(p, r, 8.3334519073e-3f);
    p = __fmaf_rn(p, r, 4.1665795894e-2f);
    p = __fmaf_rn(p, r, 1.6666665459e-1f);
    p = __fmaf_rn(p, r, 5.0000001201e-1f);
    p = __fmaf_rn(p, r2, r);
    p = __fadd_rn(p, 1.0f);
    int mi = (int)m;
    return p * __int_as_float((mi + 127) << 23);
}

// ---------------- weight prep: rpn_w [oc][ic][tap] -> f32 [tap][ic][oc] ------
__global__ void prep_wcv(const float* __restrict__ rpn_w, float* __restrict__ wcv) {
    int t = blockIdx.x * 256 + threadIdx.x;
    if (t >= 589824) return;
    int tap = t / 65536, rem = t % 65536, ic = rem / 256, oc = rem % 256;
    wcv[t] = rpn_w[oc * 2304 + ic * 9 + tap];
}

// ---------------- feature pad: featP[ic][130][132], +1 halo of literal zeros -
// fma(0, w, acc) == acc exactly => identical chain to the bounds-checked r12.
__global__ void prep_pad(const float* __restrict__ feat, float* __restrict__ featP) {
    int t = blockIdx.x * 256 + threadIdx.x;
    if (t >= 256 * 130 * 132) return;
    int ic = t / 17160, rem = t % 17160, y = rem / 132, x = rem % 132;
    int sy = y - 1, sx = x - 1;
    float v = 0.f;
    if (sy >= 0 && sy < 128 && sx >= 0 && sx < 128)
        v = feat[ic * 16384 + sy * 128 + sx];
    featP[t] = v;
}

// ---------------- conv3x3: 8px x 4oc per thread, padded features -------------
// Bit-exact r12 chain per (px,oc): ONE f32 acc, k=(tap, ic 0..255) ascending.
// Block = 16x16-px tile x 32 oc. Thread: 8 consecutive x  x 4 consecutive oc.
// Weights: 32KB LDS per tap, one broadcast ds_read_b128 per (thread, ic).
// Grid 512: blk = slot*8 + band  (band = blk%8 -> XCD heuristic); band = tile
// row => per-XCD feature band ~2.6MB stays L2-resident across all 9 taps.
__global__ __launch_bounds__(256, 2) void conv3x3(const float* __restrict__ featP,
                                                  const float* __restrict__ wcv,
                                                  const float* __restrict__ rpn_b,
                                                  float* __restrict__ xd) {
    __shared__ float sW[8192];                 // [ic][32 oc] for current tap
    const int band = blockIdx.x & 7;           // tile row (XCD-pinned)
    const int slot = blockIdx.x >> 3;          // 0..63
    const int tx = slot & 7, ocb = slot >> 3;  // tile col, oc-block(32)
    const int oc0 = ocb * 32;
    const int tid = threadIdx.x;
    const int ocg = tid >> 5;                  // 0..7 -> 4 oc each
    const int oct = tid & 31;                  // 0..31: row = oct>>1, xhalf = oct&1
    const int py = oct >> 1, px0 = (oct & 1) * 8;
    const int gy = band * 16 + py, gx0 = tx * 16 + px0;
    const int ocB = oc0 + ocg * 4;
    float acc[8][4];
#pragma unroll
    for (int p = 0; p < 8; ++p)
#pragma unroll
        for (int o = 0; o < 4; ++o) acc[p][o] = 0.f;
#pragma unroll
    for (int tap = 0; tap < 9; ++tap) {        // k-major: tap (ky,kx)
        __syncthreads();
        for (int idx = tid; idx < 8192; idx += 256)
            sW[idx] = wcv[tap * 65536 + (idx >> 5) * 256 + oc0 + (idx & 31)];
        __syncthreads();
        // padded row gy+dy (== gy+dy-1 source + 1 pad), col gx0+dx
        const float* fp = featP + (size_t)(gy + tap / 3) * 132 + (gx0 + tap % 3);
        const float* wl = sW + ocg * 4;
        for (int ic = 0; ic < 256; ++ic) {     // k-minor: ic ascending
            const float* f8 = fp + (size_t)ic * 17160;
            float4a fA = *(const float4a*)(f8);
            float4a fB = *(const float4a*)(f8 + 4);
            float4a w4 = *(const float4a*)(wl + ic * 32);   // broadcast b128
#pragma unroll
            for (int p = 0; p < 4; ++p)
#pragma unroll
                for (int o = 0; o < 4; ++o)
                    acc[p][o] = __fmaf_rn(fA[p], w4[o], acc[p][o]);
#pragma unroll
            for (int p = 0; p < 4; ++p)
#pragma unroll
                for (int o = 0; o < 4; ++o)
                    acc[4 + p][o] = __fmaf_rn(fB[p], w4[o], acc[4 + p][o]);
        }
    }
#pragma unroll
    for (int p = 0; p < 8; ++p) {
        float* op = xd + (size_t)(gy * 128 + gx0 + p) * 256 + ocB;
#pragma unroll
        for (int o = 0; o < 4; ++o) {
            float v = __fadd_rn(acc[p][o], rpn_b[ocB + o]);
            op[o] = v > 0.f ? v : 0.f;
        }
    }
}

// ---------------- heads: 1x1 convs, k=ic sequential f32 FMA (float4 loads) ---
__global__ __launch_bounds__(256, 1) void heads_seq(const float* __restrict__ xd,
                                                    const float* __restrict__ cls_w,
                                                    const float* __restrict__ box_w,
                                                    float* __restrict__ dots) {
    __shared__ float sX[4][260];
    const int tid = threadIdx.x;
    const int pix0 = blockIdx.x * 4;
    for (int idx = tid; idx < 1024; idx += 256)
        sX[idx >> 8][idx & 255] = xd[(size_t)(pix0 + (idx >> 8)) * 256 + (idx & 255)];
    __syncthreads();
    if (tid < 216) {
        const int pl = tid / 54, o = tid % 54;
        const float* wr = (o < 18) ? (cls_w + o * 256) : (box_w + (o - 18) * 256);
        const float4* x4 = (const float4*)&sX[pl][0];
        const float4* w4 = (const float4*)wr;
        float acc = 0.f;
        for (int q = 0; q < 64; ++q) {
            float4 xv = x4[q];
            float4 wv = w4[q];
            acc = __fmaf_rn(xv.x, wv.x, acc);
            acc = __fmaf_rn(xv.y, wv.y, acc);
            acc = __fmaf_rn(xv.z, wv.z, acc);
            acc = __fmaf_rn(xv.w, wv.w, acc);
        }
        dots[(size_t)(pix0 + pl) * 54 + o] = acc;
    }
}

// ---------------- decode: stepwise-F32 softmax + box decode, XLA exp ---------
__global__ __launch_bounds__(256, 1) void decode(const float* __restrict__ dots,
                                                 const float* __restrict__ cls_b,
                                                 const float* __restrict__ box_b,
                                                 float4* __restrict__ boxes,
                                                 u64* __restrict__ keys) {
    const int pix = blockIdx.x * 256 + threadIdx.x;
    if (pix >= 16384) return;
    const float* dt = dots + (size_t)pix * 54;
    float d[54];
#pragma unroll
    for (int i = 0; i < 54; ++i)
        d[i] = __fadd_rn(dt[i], (i < 18 ? cls_b[i] : box_b[i - 18]));
    float m = d[0];
#pragma unroll
    for (int i = 1; i < 18; ++i) m = fmaxf(m, d[i]);
    float e[18];
#pragma unroll
    for (int i = 0; i < 18; ++i) e[i] = exp_xla(__fsub_rn(d[i], m));
    float s = e[0];
#pragma unroll
    for (int i = 1; i < 18; ++i) s = __fadd_rn(s, e[i]);
    const int y = pix >> 7, x = pix & 127;
    const float shx = (float)(x * 32), shy = (float)(y * 32);
    const float AW[9] = {368.f, 736.f, 1472.f, 256.f, 512.f, 1024.f, 176.f, 352.f, 704.f};
    const float AH[9] = {192.f, 384.f, 768.f, 256.f, 512.f, 1024.f, 352.f, 704.f, 1408.f};
#pragma unroll
    for (int a = 0; a < 9; ++a) {
        float score = e[9 + a] / s;
        float wa = AW[a], ha = AH[a];
        float cxa = __fadd_rn(shx, 7.5f), cya = __fadd_rn(shy, 7.5f);
        float dx = d[18 + 4 * a], dyy = d[19 + 4 * a];
        float dw = d[20 + 4 * a], dh = d[21 + 4 * a];
        float cx = __fadd_rn(__fmul_rn(dx, wa), cxa);
        float cy = __fadd_rn(__fmul_rn(dyy, ha), cya);
        float pw = __fmul_rn(wa, exp_xla(dw));
        float ph = __fmul_rn(ha, exp_xla(dh));
        float hx = __fmul_rn(0.5f, pw), hy = __fmul_rn(0.5f, ph);
        float x1 = fminf(fmaxf(__fsub_rn(cx, hx), 0.f), 4095.f);
        float y1 = fminf(fmaxf(__fsub_rn(cy, hy), 0.f), 4095.f);
        float x2 = fminf(fmaxf(__fadd_rn(cx, hx), 0.f), 4095.f);
        float y2 = fminf(fmaxf(__fadd_rn(cy, hy), 0.f), 4095.f);
        float vw = __fadd_rn(__fsub_rn(x2, x1), 1.0f);
        float vh = __fadd_rn(__fsub_rn(y2, y1), 1.0f);
        bool valid = (vw >= 16.0f) && (vh >= 16.0f);
        int i = pix * 9 + a;
        boxes[i] = make_float4(x1, y1, x2, y2);
        u64 k;
        if (valid) {
            u32 b = __float_as_uint(score);
            k = ((u64)(u32)~(b | 0x80000000u) << 32) | (u32)i;
        } else {
            k = (0xFFFFFFFFULL << 32) | (u32)i;
        }
        keys[i] = k;
    }
}

// ---------------- radix select: 8 passes of 8 bits, LDS histograms -----------
__global__ __launch_bounds__(256) void hist8(const u64* __restrict__ keys,
                                             u32* __restrict__ ghist,
                                             const u64* __restrict__ pfx, int pass) {
    __shared__ u32 lh[256];
    lh[threadIdx.x] = 0;
    __syncthreads();
    const u64 pref = *pfx;
    const int shift = 56 - 8 * pass;
    for (int i = blockIdx.x * 256 + threadIdx.x; i < 147456; i += 64 * 256) {
        u64 k = keys[i];
        bool match = (pass == 0) || ((k >> (shift + 8)) == pref);
        if (match) atomicAdd(&lh[(u32)(k >> shift) & 0xFFu], 1u);
    }
    __syncthreads();
    if (lh[threadIdx.x]) atomicAdd(&ghist[threadIdx.x], lh[threadIdx.x]);
}

__global__ __launch_bounds__(256) void scan8(const u32* __restrict__ ghist,
                                             u64* pfx, u32* tgt, int pass) {
    __shared__ u32 h[256];
    __shared__ u32 incl[256];
    const int t = threadIdx.x;
    u32 target = (pass == 0) ? 6000u : *tgt;
    u64 p0 = (pass == 0) ? 0ULL : *pfx;
    h[t] = ghist[t];
    incl[t] = h[t];
    __syncthreads();
    for (int off = 1; off < 256; off <<= 1) {
        u32 v = (t >= off) ? incl[t - off] : 0u;
        __syncthreads();
        incl[t] += v;
        __syncthreads();
    }
    u32 before = incl[t] - h[t];
    if (before < target && target <= incl[t]) {
        *pfx = (p0 << 8) | (u64)t;
        *tgt = target - before;
    }
}

__global__ void compact(const u64* __restrict__ keys, const u64* __restrict__ kstar,
                        u32* count, u64* __restrict__ ckey, u32* __restrict__ cidx) {
    int i = blockIdx.x * 256 + threadIdx.x;
    if (i >= 147456) return;
    u64 k = keys[i];
    if (k <= *kstar) {
        u32 pos = atomicAdd(count, 1u);
        if (pos < 6144) { ckey[pos] = k; cidx[pos] = (u32)(k & 0xFFFFFFFFu); }
    }
}

// ---------------- exact rank (keys unique) + gather sorted top-6000 ----------
__global__ __launch_bounds__(256) void rank_scatter(const u64* __restrict__ ckey,
                                                    const u32* __restrict__ cidx,
                                                    const u32* __restrict__ count,
                                                    const float4* __restrict__ boxes,
                                                    float4* __restrict__ tb,
                                                    float* __restrict__ tsc) {
    __shared__ u64 LK[6144];
    int N = (int)*count; if (N > 6144) N = 6144;
    for (int i = threadIdx.x; i < N; i += 256) LK[i] = ckey[i];
    __syncthreads();
    int e = blockIdx.x * 256 + threadIdx.x;
    if (e >= N) return;
    u64 myK = LK[e];
    u32 myI = cidx[e];
    int rank = 0;
    for (int c = 0; c < N; ++c) rank += (LK[c] < myK);
    if (rank < 6000) {
        tb[rank] = boxes[myI];
        u32 hi = (u32)(myK >> 32);
        tsc[rank] = (hi == 0xFFFFFFFFu) ? -__builtin_inff()
                                        : __uint_as_float(~hi & 0x7FFFFFFFu);
    }
}

// ---------------- alive bitmask init -----------------------------------------
__global__ void alive_init(const float* __restrict__ tsc, u64* __restrict__ alive0) {
    int r = blockIdx.x * 256 + threadIdx.x;
    bool a = false;
    if (r < 6000) a = tsc[r] > -__builtin_inff();
    u64 b = __ballot(a);
    if ((threadIdx.x & 63) == 0) alive0[r >> 6] = b;
}

// ---------------- suppression bitmask: m[j][i] = iou(tb[j],tb[i]) > 0.7 ------
__global__ __launch_bounds__(256) void nms_mask(const float4* __restrict__ tb,
                                                u64* __restrict__ mask) {
    int tid = blockIdx.x * 256 + threadIdx.x;
    if (tid >= 6000 * 94) return;
    int j = tid / 94, w = tid % 94;
    float4 bj = tb[j];
    float arJ = __fmul_rn(__fadd_rn(__fsub_rn(bj.z, bj.x), 1.0f),
                          __fadd_rn(__fsub_rn(bj.w, bj.y), 1.0f));
    u64 m = 0;
    int base = w * 64;
#pragma unroll 4
    for (int b = 0; b < 64; ++b) {
        int i = base + b;
        if (i >= 6000) break;
        float4 bi = tb[i];
        float arI = __fmul_rn(__fadd_rn(__fsub_rn(bi.z, bi.x), 1.0f),
                              __fadd_rn(__fsub_rn(bi.w, bi.y), 1.0f));
        float xx1 = fmaxf(bj.x, bi.x), yy1 = fmaxf(bj.y, bi.y);
        float xx2 = fminf(bj.z, bi.z), yy2 = fminf(bj.w, bi.w);
        float ww = fmaxf(__fadd_rn(__fsub_rn(xx2, xx1), 1.0f), 0.0f);
        float hh = fmaxf(__fadd_rn(__fsub_rn(yy2, yy1), 1.0f), 0.0f);
        float inter = __fmul_rn(ww, hh);
        float uni = __fsub_rn(__fadd_rn(arJ, arI), inter);
        float iou = inter / uni;
        if (iou > 0.7f) m |= (1ULL << b);
    }
    mask[(size_t)j * 96 + w] = m;
}

// ---------------- sequential NMS scan with 4-slot row prefetch ---------------
__global__ __launch_bounds__(64, 1) void nms_seq(const u64* __restrict__ alive0,
                                                 const u64* __restrict__ mask,
                                                 const float4* __restrict__ tb,
                                                 float* __restrict__ out) {
    const int lane = threadIdx.x;
    u64 wl = alive0[lane];
    u64 wh = (lane < 30) ? alive0[64 + lane] : 0ULL;
    int cj[4] = {-1, -1, -1, -1};
    u64 cl[4] = {0, 0, 0, 0}, ch[4] = {0, 0, 0, 0};
    for (int k = 0; k < 1000; ++k) {
        int j;
        {
            u64 blo = __ballot(wl != 0ULL);
            if (blo) {
                int l = __ffsll((long long)blo) - 1;
                u64 w = __shfl(wl, l);
                j = l * 64 + __ffsll((long long)w) - 1;
            } else {
                u64 bhi = __ballot(wh != 0ULL);
                if (!bhi) break;
                int l = __ffsll((long long)bhi) - 1;
                u64 w = __shfl(wh, l);
                j = (64 + l) * 64 + __ffsll((long long)w) - 1;
            }
        }
        if (lane == 0) {
            float4 bj = tb[j];
            out[k * 5 + 1] = bj.x;
            out[k * 5 + 2] = bj.y;
            out[k * 5 + 3] = bj.z;
            out[k * 5 + 4] = bj.w;
        }
        u64 rl, rh;
        int s = (j == cj[0]) ? 0 : (j == cj[1]) ? 1 : (j == cj[2]) ? 2
              : (j == cj[3]) ? 3 : -1;
        if (s >= 0) {
            rl = cl[s]; rh = ch[s];
        } else {
            rl = mask[(size_t)j * 96 + lane];
            rh = (lane < 30) ? mask[(size_t)j * 96 + 64 + lane] : 0ULL;
        }
        const int jw = j >> 6, jb = j & 63;
        u64 ml = wl, mh = wh;
        if (lane < jw) ml = 0;
        if (lane == jw) ml = (jb == 63) ? 0ULL : (ml & (~0ULL << (jb + 1)));
        if (64 + lane < jw) mh = 0;
        if (64 + lane == jw) mh = (jb == 63) ? 0ULL : (mh & (~0ULL << (jb + 1)));
#pragma unroll
        for (int q = 0; q < 4; ++q) {
            int c = -1;
            u64 blo = __ballot(ml != 0ULL);
            if (blo) {
                int l = __ffsll((long long)blo) - 1;
                u64 w = __shfl(ml, l);
                c = l * 64 + __ffsll((long long)w) - 1;
            } else {
                u64 bhi = __ballot(mh != 0ULL);
                if (bhi) {
                    int l = __ffsll((long long)bhi) - 1;
                    u64 w = __shfl(mh, l);
                    c = (64 + l) * 64 + __ffsll((long long)w) - 1;
                }
            }
            cj[q] = c;
            if (c >= 0) {
                int cw = c >> 6, cb = c & 63;
                if (cw < 64) { if (lane == cw) ml &= ~(1ULL << cb); }
                else         { if (lane == cw - 64) mh &= ~(1ULL << cb); }
                cl[q] = mask[(size_t)c * 96 + lane];
                ch[q] = (lane < 30) ? mask[(size_t)c * 96 + 64 + lane] : 0ULL;
            }
        }
        wl &= ~rl;
        if (lane < 30) wh &= ~rh;
    }
}

// ---------------- host ----------------
extern "C" void kernel_launch(void* const* d_in, const int* in_sizes, int n_in,
                              void* d_out, int out_size, void* d_ws, size_t ws_size,
                              hipStream_t stream) {
    const float *feat = nullptr, *rpn_w = nullptr, *rpn_b = nullptr;
    const float *cls_w = nullptr, *cls_b = nullptr, *box_w = nullptr, *box_b = nullptr;
    for (int i = 0; i < n_in; ++i) {
        switch (in_sizes[i]) {
            case 4194304: feat  = (const float*)d_in[i]; break;
            case 589824:  rpn_w = (const float*)d_in[i]; break;
            case 256:     rpn_b = (const float*)d_in[i]; break;
            case 4608:    cls_w = (const float*)d_in[i]; break;
            case 18:      cls_b = (const float*)d_in[i]; break;
            case 9216:    box_w = (const float*)d_in[i]; break;
            case 36:      box_b = (const float*)d_in[i]; break;
            default: break;  // image dims hardcoded (4096)
        }
    }

    char* w = (char*)d_ws;
    u64* pfx       = (u64*)(w + OFF_CTL);
    u32* tgt       = (u32*)(w + OFF_CTL + 8);
    u32* ctlCount  = (u32*)(w + OFF_CTL + 12);
    u32* hist      = (u32*)(w + OFF_HIST);
    float* dots    = (float*)(w + OFF_DOTS);
    float* wcv     = (float*)(w + OFF_WCV);
    float* xd      = (float*)(w + OFF_XD);
    float4* boxes  = (float4*)(w + OFF_BOX);
    u64* keys      = (u64*)(w + OFF_KEYS);
    u64* ckey      = (u64*)(w + OFF_CKEY);
    u32* cidx      = (u32*)(w + OFF_CIDX);
    float4* tb     = (float4*)(w + OFF_TB);
    float* tsc     = (float*)(w + OFF_TSC);
    u64* alive0    = (u64*)(w + OFF_ALIVE);
    u64* mask      = (u64*)(w + OFF_MASK);
    float* featP   = (float*)(w + OFF_FPAD);

    hipMemsetAsync(d_ws, 0, OFF_HIST + 8 * 256 * 4, stream);  // ctl + 8 hists
    hipMemsetAsync(d_out, 0, (size_t)out_size * sizeof(float), stream);

    prep_wcv<<<2304, 256, 0, stream>>>(rpn_w, wcv);
    prep_pad<<<17160, 256, 0, stream>>>(feat, featP);
    conv3x3<<<512, 256, 0, stream>>>(featP, wcv, rpn_b, xd);
    heads_seq<<<4096, 256, 0, stream>>>(xd, cls_w, box_w, dots);
    decode<<<64, 256, 0, stream>>>(dots, cls_b, box_b, boxes, keys);
    for (int p = 0; p < 8; ++p) {
        hist8<<<64, 256, 0, stream>>>(keys, hist + p * 256, pfx, p);
        scan8<<<1, 256, 0, stream>>>(hist + p * 256, pfx, tgt, p);
    }
    compact<<<576, 256, 0, stream>>>(keys, pfx, ctlCount, ckey, cidx);
    rank_scatter<<<24, 256, 0, stream>>>(ckey, cidx, ctlCount, boxes, tb, tsc);
    alive_init<<<24, 256, 0, stream>>>(tsc, alive0);
    nms_mask<<<2204, 256, 0, stream>>>(tb, mask);
    nms_seq<<<1, 64, 0, stream>>>(alive0, mask, tb, (float*)d_out);
}

// Round 18
// 1412.736 us; speedup vs baseline: 2.3589x; 1.5255x over previous
//
#include <hip/hip_runtime.h>
#include <stdint.h>
#include <math.h>

typedef unsigned long long u64;
typedef unsigned int u32;
typedef float float4a __attribute__((ext_vector_type(4), aligned(4)));

// ---------------- workspace layout (bytes) ----------------
static const size_t OFF_CTL   = 0;          // [0]=u64 prefix/kstar, [8]=u32 target, [12]=u32 count
static const size_t OFF_HIST  = 1024;       // 8 passes * 256 * 4 = 8 KB
static const size_t OFF_DOTS  = 1049600;    // 16384*54*4
static const size_t OFF_WCV   = 4588544;    // 589824*4  [tap][ic][oc]
static const size_t OFF_XD    = 6947840;    // 16384*256*4 (conv out f32, HWC)
static const size_t OFF_BOX   = 23725056;   // 147456*16 (float4)
static const size_t OFF_KEYS  = 26084352;   // 147456*8
static const size_t OFF_CKEY  = 27264000;   // 6144*8
static const size_t OFF_CIDX  = 27313152;   // 6144*4
static const size_t OFF_TB    = 27337728;   // 6000*16
static const size_t OFF_TSC   = 27433728;   // 6000*4
static const size_t OFF_ALIVE = 27458048;   // 128*8
static const size_t OFF_MASK  = 27459072;   // 6000*96*8 = 4608000
static const size_t OFF_FPAD  = 32067584;   // 256*130*132*4 = 17571840  end ~49.6 MB

// XLA-CPU / Eigen / Cephes f32 exp (FMA form) — bit-matches the np reference.
__device__ __forceinline__ float exp_xla(float x) {
    float m = floorf(__fmaf_rn(x, 1.44269504088896341f, 0.5f));
    float r = __fmaf_rn(m, -0.693359375f, x);
    r = __fmaf_rn(m, 2.12194440e-4f, r);
    float r2 = r * r;
    float p = 1.9875691500e-4f;
    p = __fmaf_rn(p, r, 1.3981999507e-3f);
    p = __fmaf_rn(p, r, 8.3334519073e-3f);
    p = __fmaf_rn(p, r, 4.1665795894e-2f);
    p = __fmaf_rn(p, r, 1.6666665459e-1f);
    p = __fmaf_rn(p, r, 5.0000001201e-1f);
    p = __fmaf_rn(p, r2, r);
    p = __fadd_rn(p, 1.0f);
    int mi = (int)m;
    return p * __int_as_float((mi + 127) << 23);
}

// ---------------- weight prep: rpn_w [oc][ic][tap] -> f32 [tap][ic][oc] ------
__global__ void prep_wcv(const float* __restrict__ rpn_w, float* __restrict__ wcv) {
    int t = blockIdx.x * 256 + threadIdx.x;
    if (t >= 589824) return;
    int tap = t / 65536, rem = t % 65536, ic = rem / 256, oc = rem % 256;
    wcv[t] = rpn_w[oc * 2304 + ic * 9 + tap];
}

// ---------------- feature pad: featP[ic][130][132], +1 halo of literal zeros -
__global__ void prep_pad(const float* __restrict__ feat, float* __restrict__ featP) {
    int t = blockIdx.x * 256 + threadIdx.x;
    if (t >= 256 * 130 * 132) return;
    int ic = t / 17160, rem = t % 17160, y = rem / 132, x = rem % 132;
    int sy = y - 1, sx = x - 1;
    float v = 0.f;
    if (sy >= 0 && sy < 128 && sx >= 0 && sx < 128)
        v = feat[ic * 16384 + sy * 128 + sx];
    featP[t] = v;
}

// ---------------- conv3x3: 8px x 4oc per thread, padded features -------------
// Bit-exact r12 chain per (px,oc): ONE f32 acc, k=(tap, ic 0..255) ascending.
__global__ __launch_bounds__(256, 2) void conv3x3(const float* __restrict__ featP,
                                                  const float* __restrict__ wcv,
                                                  const float* __restrict__ rpn_b,
                                                  float* __restrict__ xd) {
    __shared__ float sW[8192];                 // [ic][32 oc] for current tap
    const int band = blockIdx.x & 7;           // tile row (XCD-pinned)
    const int slot = blockIdx.x >> 3;          // 0..63
    const int tx = slot & 7, ocb = slot >> 3;  // tile col, oc-block(32)
    const int oc0 = ocb * 32;
    const int tid = threadIdx.x;
    const int ocg = tid >> 5;                  // 0..7 -> 4 oc each
    const int oct = tid & 31;
    const int py = oct >> 1, px0 = (oct & 1) * 8;
    const int gy = band * 16 + py, gx0 = tx * 16 + px0;
    const int ocB = oc0 + ocg * 4;
    float acc[8][4];
#pragma unroll
    for (int p = 0; p < 8; ++p)
#pragma unroll
        for (int o = 0; o < 4; ++o) acc[p][o] = 0.f;
#pragma unroll
    for (int tap = 0; tap < 9; ++tap) {        // k-major: tap (ky,kx)
        __syncthreads();
        for (int idx = tid; idx < 8192; idx += 256)
            sW[idx] = wcv[tap * 65536 + (idx >> 5) * 256 + oc0 + (idx & 31)];
        __syncthreads();
        const float* fp = featP + (size_t)(gy + tap / 3) * 132 + (gx0 + tap % 3);
        const float* wl = sW + ocg * 4;
        for (int ic = 0; ic < 256; ++ic) {     // k-minor: ic ascending
            const float* f8 = fp + (size_t)ic * 17160;
            float4a fA = *(const float4a*)(f8);
            float4a fB = *(const float4a*)(f8 + 4);
            float4a w4 = *(const float4a*)(wl + ic * 32);   // broadcast b128
#pragma unroll
            for (int p = 0; p < 4; ++p)
#pragma unroll
                for (int o = 0; o < 4; ++o)
                    acc[p][o] = __fmaf_rn(fA[p], w4[o], acc[p][o]);
#pragma unroll
            for (int p = 0; p < 4; ++p)
#pragma unroll
                for (int o = 0; o < 4; ++o)
                    acc[4 + p][o] = __fmaf_rn(fB[p], w4[o], acc[4 + p][o]);
        }
    }
#pragma unroll
    for (int p = 0; p < 8; ++p) {
        float* op = xd + (size_t)(gy * 128 + gx0 + p) * 256 + ocB;
#pragma unroll
        for (int o = 0; o < 4; ++o) {
            float v = __fadd_rn(acc[p][o], rpn_b[ocB + o]);
            op[o] = v > 0.f ? v : 0.f;
        }
    }
}

// ---------------- heads: 1x1 convs, k=ic sequential f32 FMA (float4 loads) ---
__global__ __launch_bounds__(256, 1) void heads_seq(const float* __restrict__ xd,
                                                    const float* __restrict__ cls_w,
                                                    const float* __restrict__ box_w,
                                                    float* __restrict__ dots) {
    __shared__ float sX[4][260];
    const int tid = threadIdx.x;
    const int pix0 = blockIdx.x * 4;
    for (int idx = tid; idx < 1024; idx += 256)
        sX[idx >> 8][idx & 255] = xd[(size_t)(pix0 + (idx >> 8)) * 256 + (idx & 255)];
    __syncthreads();
    if (tid < 216) {
        const int pl = tid / 54, o = tid % 54;
        const float* wr = (o < 18) ? (cls_w + o * 256) : (box_w + (o - 18) * 256);
        const float4* x4 = (const float4*)&sX[pl][0];
        const float4* w4 = (const float4*)wr;
        float acc = 0.f;
        for (int q = 0; q < 64; ++q) {
            float4 xv = x4[q];
            float4 wv = w4[q];
            acc = __fmaf_rn(xv.x, wv.x, acc);
            acc = __fmaf_rn(xv.y, wv.y, acc);
            acc = __fmaf_rn(xv.z, wv.z, acc);
            acc = __fmaf_rn(xv.w, wv.w, acc);
        }
        dots[(size_t)(pix0 + pl) * 54 + o] = acc;
    }
}

// ---------------- decode: stepwise-F32 softmax + box decode, XLA exp ---------
__global__ __launch_bounds__(256, 1) void decode(const float* __restrict__ dots,
                                                 const float* __restrict__ cls_b,
                                                 const float* __restrict__ box_b,
                                                 float4* __restrict__ boxes,
                                                 u64* __restrict__ keys) {
    const int pix = blockIdx.x * 256 + threadIdx.x;
    if (pix >= 16384) return;
    const float* dt = dots + (size_t)pix * 54;
    float d[54];
#pragma unroll
    for (int i = 0; i < 54; ++i)
        d[i] = __fadd_rn(dt[i], (i < 18 ? cls_b[i] : box_b[i - 18]));
    float m = d[0];
#pragma unroll
    for (int i = 1; i < 18; ++i) m = fmaxf(m, d[i]);
    float e[18];
#pragma unroll
    for (int i = 0; i < 18; ++i) e[i] = exp_xla(__fsub_rn(d[i], m));
    float s = e[0];
#pragma unroll
    for (int i = 1; i < 18; ++i) s = __fadd_rn(s, e[i]);
    const int y = pix >> 7, x = pix & 127;
    const float shx = (float)(x * 32), shy = (float)(y * 32);
    const float AW[9] = {368.f, 736.f, 1472.f, 256.f, 512.f, 1024.f, 176.f, 352.f, 704.f};
    const float AH[9] = {192.f, 384.f, 768.f, 256.f, 512.f, 1024.f, 352.f, 704.f, 1408.f};
#pragma unroll
    for (int a = 0; a < 9; ++a) {
        float score = e[9 + a] / s;
        float wa = AW[a], ha = AH[a];
        float cxa = __fadd_rn(shx, 7.5f), cya = __fadd_rn(shy, 7.5f);
        float dx = d[18 + 4 * a], dyy = d[19 + 4 * a];
        float dw = d[20 + 4 * a], dh = d[21 + 4 * a];
        float cx = __fadd_rn(__fmul_rn(dx, wa), cxa);
        float cy = __fadd_rn(__fmul_rn(dyy, ha), cya);
        float pw = __fmul_rn(wa, exp_xla(dw));
        float ph = __fmul_rn(ha, exp_xla(dh));
        float hx = __fmul_rn(0.5f, pw), hy = __fmul_rn(0.5f, ph);
        float x1 = fminf(fmaxf(__fsub_rn(cx, hx), 0.f), 4095.f);
        float y1 = fminf(fmaxf(__fsub_rn(cy, hy), 0.f), 4095.f);
        float x2 = fminf(fmaxf(__fadd_rn(cx, hx), 0.f), 4095.f);
        float y2 = fminf(fmaxf(__fadd_rn(cy, hy), 0.f), 4095.f);
        float vw = __fadd_rn(__fsub_rn(x2, x1), 1.0f);
        float vh = __fadd_rn(__fsub_rn(y2, y1), 1.0f);
        bool valid = (vw >= 16.0f) && (vh >= 16.0f);
        int i = pix * 9 + a;
        boxes[i] = make_float4(x1, y1, x2, y2);
        u64 k;
        if (valid) {
            u32 b = __float_as_uint(score);
            k = ((u64)(u32)~(b | 0x80000000u) << 32) | (u32)i;
        } else {
            k = (0xFFFFFFFFULL << 32) | (u32)i;
        }
        keys[i] = k;
    }
}

// ---------------- radix select: 8 passes of 8 bits, LDS histograms -----------
__global__ __launch_bounds__(256) void hist8(const u64* __restrict__ keys,
                                             u32* __restrict__ ghist,
                                             const u64* __restrict__ pfx, int pass) {
    __shared__ u32 lh[256];
    lh[threadIdx.x] = 0;
    __syncthreads();
    const u64 pref = *pfx;
    const int shift = 56 - 8 * pass;
    for (int i = blockIdx.x * 256 + threadIdx.x; i < 147456; i += 64 * 256) {
        u64 k = keys[i];
        bool match = (pass == 0) || ((k >> (shift + 8)) == pref);
        if (match) atomicAdd(&lh[(u32)(k >> shift) & 0xFFu], 1u);
    }
    __syncthreads();
    if (lh[threadIdx.x]) atomicAdd(&ghist[threadIdx.x], lh[threadIdx.x]);
}

__global__ __launch_bounds__(256) void scan8(const u32* __restrict__ ghist,
                                             u64* pfx, u32* tgt, int pass) {
    __shared__ u32 h[256];
    __shared__ u32 incl[256];
    const int t = threadIdx.x;
    u32 target = (pass == 0) ? 6000u : *tgt;
    u64 p0 = (pass == 0) ? 0ULL : *pfx;
    h[t] = ghist[t];
    incl[t] = h[t];
    __syncthreads();
    for (int off = 1; off < 256; off <<= 1) {
        u32 v = (t >= off) ? incl[t - off] : 0u;
        __syncthreads();
        incl[t] += v;
        __syncthreads();
    }
    u32 before = incl[t] - h[t];
    if (before < target && target <= incl[t]) {
        *pfx = (p0 << 8) | (u64)t;
        *tgt = target - before;
    }
}

__global__ void compact(const u64* __restrict__ keys, const u64* __restrict__ kstar,
                        u32* count, u64* __restrict__ ckey, u32* __restrict__ cidx) {
    int i = blockIdx.x * 256 + threadIdx.x;
    if (i >= 147456) return;
    u64 k = keys[i];
    if (k <= *kstar) {
        u32 pos = atomicAdd(count, 1u);
        if (pos < 6144) { ckey[pos] = k; cidx[pos] = (u32)(k & 0xFFFFFFFFu); }
    }
}

// ---------------- exact rank (keys unique) + gather sorted top-6000 ----------
__global__ __launch_bounds__(256) void rank_scatter(const u64* __restrict__ ckey,
                                                    const u32* __restrict__ cidx,
                                                    const u32* __restrict__ count,
                                                    const float4* __restrict__ boxes,
                                                    float4* __restrict__ tb,
                                                    float* __restrict__ tsc) {
    __shared__ u64 LK[6144];
    int N = (int)*count; if (N > 6144) N = 6144;
    for (int i = threadIdx.x; i < N; i += 256) LK[i] = ckey[i];
    __syncthreads();
    int e = blockIdx.x * 256 + threadIdx.x;
    if (e >= N) return;
    u64 myK = LK[e];
    u32 myI = cidx[e];
    int rank = 0;
    for (int c = 0; c < N; ++c) rank += (LK[c] < myK);
    if (rank < 6000) {
        tb[rank] = boxes[myI];
        u32 hi = (u32)(myK >> 32);
        tsc[rank] = (hi == 0xFFFFFFFFu) ? -__builtin_inff()
                                        : __uint_as_float(~hi & 0x7FFFFFFFu);
    }
}

// ---------------- alive bitmask init -----------------------------------------
__global__ void alive_init(const float* __restrict__ tsc, u64* __restrict__ alive0) {
    int r = blockIdx.x * 256 + threadIdx.x;
    bool a = false;
    if (r < 6000) a = tsc[r] > -__builtin_inff();
    u64 b = __ballot(a);
    if ((threadIdx.x & 63) == 0) alive0[r >> 6] = b;
}

// ---------------- suppression bitmask: m[j][i] = iou(tb[j],tb[i]) > 0.7 ------
__global__ __launch_bounds__(256) void nms_mask(const float4* __restrict__ tb,
                                                u64* __restrict__ mask) {
    int tid = blockIdx.x * 256 + threadIdx.x;
    if (tid >= 6000 * 94) return;
    int j = tid / 94, w = tid % 94;
    float4 bj = tb[j];
    float arJ = __fmul_rn(__fadd_rn(__fsub_rn(bj.z, bj.x), 1.0f),
                          __fadd_rn(__fsub_rn(bj.w, bj.y), 1.0f));
    u64 m = 0;
    int base = w * 64;
#pragma unroll 4
    for (int b = 0; b < 64; ++b) {
        int i = base + b;
        if (i >= 6000) break;
        float4 bi = tb[i];
        float arI = __fmul_rn(__fadd_rn(__fsub_rn(bi.z, bi.x), 1.0f),
                              __fadd_rn(__fsub_rn(bi.w, bi.y), 1.0f));
        float xx1 = fmaxf(bj.x, bi.x), yy1 = fmaxf(bj.y, bi.y);
        float xx2 = fminf(bj.z, bi.z), yy2 = fminf(bj.w, bi.w);
        float ww = fmaxf(__fadd_rn(__fsub_rn(xx2, xx1), 1.0f), 0.0f);
        float hh = fmaxf(__fadd_rn(__fsub_rn(yy2, yy1), 1.0f), 0.0f);
        float inter = __fmul_rn(ww, hh);
        float uni = __fsub_rn(__fadd_rn(arJ, arI), inter);
        float iou = inter / uni;
        if (iou > 0.7f) m |= (1ULL << b);
    }
    mask[(size_t)j * 96 + w] = m;
}

// ---------------- sequential NMS: monotone-j sliding prefetch ----------------
// alive bits only clear => selected j strictly increases. So the next j is
// almost always in (j, j+8]. Prefetch rows j+1..j+8 unconditionally into
// register slots (no candidate search); select via unrolled compare chain.
__global__ __launch_bounds__(64, 1) void nms_seq(const u64* __restrict__ alive0,
                                                 const u64* __restrict__ mask,
                                                 const float4* __restrict__ tb,
                                                 float* __restrict__ out) {
    const int lane = threadIdx.x;
    u64 wl = alive0[lane];
    u64 wh = (lane < 30) ? alive0[64 + lane] : 0ULL;
    u64 pl[8], ph[8];
    int pj = -1;  // slots hold rows pj+1..pj+8 = 0..7
#pragma unroll
    for (int q = 0; q < 8; ++q) {
        pl[q] = mask[(size_t)q * 96 + lane];
        ph[q] = (lane < 30) ? mask[(size_t)q * 96 + 64 + lane] : 0ULL;
    }
    for (int k = 0; k < 1000; ++k) {
        // ---- j = first alive (strictly > previous j) ----
        int j;
        {
            u64 blo = __ballot(wl != 0ULL);
            if (blo) {
                int l = __ffsll((long long)blo) - 1;
                u64 w = __shfl(wl, l);
                j = l * 64 + __ffsll((long long)w) - 1;
            } else {
                u64 bhi = __ballot(wh != 0ULL);
                if (!bhi) break;  // exhausted: remaining out rows stay 0
                int l = __ffsll((long long)bhi) - 1;
                u64 w = __shfl(wh, l);
                j = (64 + l) * 64 + __ffsll((long long)w) - 1;
            }
        }
        if (lane == 0) {
            float4 bj = tb[j];
            out[k * 5 + 1] = bj.x;
            out[k * 5 + 2] = bj.y;
            out[k * 5 + 3] = bj.z;
            out[k * 5 + 4] = bj.w;
        }
        // ---- row j: prefetched slot (hit if j-pj-1 in [0,8)) or direct ----
        const int s = j - pj - 1;
        u64 rl, rh;
        if (s >= 0 && s < 8) {
            rl = pl[0]; rh = ph[0];
#pragma unroll
            for (int q = 1; q < 8; ++q)
                if (s == q) { rl = pl[q]; rh = ph[q]; }
        } else {
            rl = mask[(size_t)j * 96 + lane];
            rh = (lane < 30) ? mask[(size_t)j * 96 + 64 + lane] : 0ULL;
        }
        // ---- prefetch rows j+1..j+8 (clamped; redundancy is L2-absorbed) ----
#pragma unroll
        for (int q = 0; q < 8; ++q) {
            int r = j + 1 + q;
            if (r > 5999) r = 5999;
            pl[q] = mask[(size_t)r * 96 + lane];
            ph[q] = (lane < 30) ? mask[(size_t)r * 96 + 64 + lane] : 0ULL;
        }
        pj = j;
        // ---- apply row j (kills j itself via iou==1) ----
        wl &= ~rl;
        if (lane < 30) wh &= ~rh;
    }
}

// ---------------- host ----------------
extern "C" void kernel_launch(void* const* d_in, const int* in_sizes, int n_in,
                              void* d_out, int out_size, void* d_ws, size_t ws_size,
                              hipStream_t stream) {
    const float *feat = nullptr, *rpn_w = nullptr, *rpn_b = nullptr;
    const float *cls_w = nullptr, *cls_b = nullptr, *box_w = nullptr, *box_b = nullptr;
    for (int i = 0; i < n_in; ++i) {
        switch (in_sizes[i]) {
            case 4194304: feat  = (const float*)d_in[i]; break;
            case 589824:  rpn_w = (const float*)d_in[i]; break;
            case 256:     rpn_b = (const float*)d_in[i]; break;
            case 4608:    cls_w = (const float*)d_in[i]; break;
            case 18:      cls_b = (const float*)d_in[i]; break;
            case 9216:    box_w = (const float*)d_in[i]; break;
            case 36:      box_b = (const float*)d_in[i]; break;
            default: break;  // image dims hardcoded (4096)
        }
    }

    char* w = (char*)d_ws;
    u64* pfx       = (u64*)(w + OFF_CTL);
    u32* tgt       = (u32*)(w + OFF_CTL + 8);
    u32* ctlCount  = (u32*)(w + OFF_CTL + 12);
    u32* hist      = (u32*)(w + OFF_HIST);
    float* dots    = (float*)(w + OFF_DOTS);
    float* wcv     = (float*)(w + OFF_WCV);
    float* xd      = (float*)(w + OFF_XD);
    float4* boxes  = (float4*)(w + OFF_BOX);
    u64* keys      = (u64*)(w + OFF_KEYS);
    u64* ckey      = (u64*)(w + OFF_CKEY);
    u32* cidx      = (u32*)(w + OFF_CIDX);
    float4* tb     = (float4*)(w + OFF_TB);
    float* tsc     = (float*)(w + OFF_TSC);
    u64* alive0    = (u64*)(w + OFF_ALIVE);
    u64* mask      = (u64*)(w + OFF_MASK);
    float* featP   = (float*)(w + OFF_FPAD);

    hipMemsetAsync(d_ws, 0, OFF_HIST + 8 * 256 * 4, stream);  // ctl + 8 hists
    hipMemsetAsync(d_out, 0, (size_t)out_size * sizeof(float), stream);

    prep_wcv<<<2304, 256, 0, stream>>>(rpn_w, wcv);
    prep_pad<<<17160, 256, 0, stream>>>(feat, featP);
    conv3x3<<<512, 256, 0, stream>>>(featP, wcv, rpn_b, xd);
    heads_seq<<<4096, 256, 0, stream>>>(xd, cls_w, box_w, dots);
    decode<<<64, 256, 0, stream>>>(dots, cls_b, box_b, boxes, keys);
    for (int p = 0; p < 8; ++p) {
        hist8<<<64, 256, 0, stream>>>(keys, hist + p * 256, pfx, p);
        scan8<<<1, 256, 0, stream>>>(hist + p * 256, pfx, tgt, p);
    }
    compact<<<576, 256, 0, stream>>>(keys, pfx, ctlCount, ckey, cidx);
    rank_scatter<<<24, 256, 0, stream>>>(ckey, cidx, ctlCount, boxes, tb, tsc);
    alive_init<<<24, 256, 0, stream>>>(tsc, alive0);
    nms_mask<<<2204, 256, 0, stream>>>(tb, mask);
    nms_seq<<<1, 64, 0, stream>>>(alive0, mask, tb, (float*)d_out);
}

// Round 19
// 1287.659 us; speedup vs baseline: 2.5881x; 1.0971x over previous
//
#include <hip/hip_runtime.h>
#include <stdint.h>
#include <math.h>

typedef unsigned long long u64;
typedef unsigned int u32;
typedef float float4a __attribute__((ext_vector_type(4), aligned(4)));

// ---------------- workspace layout (bytes) ----------------
static const size_t OFF_CTL   = 0;          // [0]=u64 prefix/kstar, [8]=u32 target, [12]=u32 count
static const size_t OFF_HIST  = 1024;       // 8 passes * 256 * 4 = 8 KB
static const size_t OFF_DOTS  = 1049600;    // 16384*54*4
static const size_t OFF_WCV   = 4588544;    // 589824*4  [tap][ic][oc]
static const size_t OFF_XD    = 6947840;    // 16384*256*4 (conv out f32, HWC)
static const size_t OFF_BOX   = 23725056;   // 147456*16 (float4)
static const size_t OFF_KEYS  = 26084352;   // 147456*8
static const size_t OFF_CKEY  = 27264000;   // 6144*8
static const size_t OFF_CIDX  = 27313152;   // 6144*4
static const size_t OFF_TB    = 27337728;   // 6000*16
static const size_t OFF_TSC   = 27433728;   // 6000*4
static const size_t OFF_ALIVE = 27458048;   // 128*8
static const size_t OFF_MASK  = 27459072;   // 6000*96*8 = 4608000
static const size_t OFF_FPAD  = 32067584;   // 256*130*132*4 = 17571840  end ~49.6 MB

// XLA-CPU / Eigen / Cephes f32 exp (FMA form) — bit-matches the np reference.
__device__ __forceinline__ float exp_xla(float x) {
    float m = floorf(__fmaf_rn(x, 1.44269504088896341f, 0.5f));
    float r = __fmaf_rn(m, -0.693359375f, x);
    r = __fmaf_rn(m, 2.12194440e-4f, r);
    float r2 = r * r;
    float p = 1.9875691500e-4f;
    p = __fmaf_rn(p, r, 1.3981999507e-3f);
    p = __fmaf_rn(p, r, 8.3334519073e-3f);
    p = __fmaf_rn(p, r, 4.1665795894e-2f);
    p = __fmaf_rn(p, r, 1.6666665459e-1f);
    p = __fmaf_rn(p, r, 5.0000001201e-1f);
    p = __fmaf_rn(p, r2, r);
    p = __fadd_rn(p, 1.0f);
    int mi = (int)m;
    return p * __int_as_float((mi + 127) << 23);
}

// ---------------- weight prep: rpn_w [oc][ic][tap] -> f32 [tap][ic][oc] ------
__global__ void prep_wcv(const float* __restrict__ rpn_w, float* __restrict__ wcv) {
    int t = blockIdx.x * 256 + threadIdx.x;
    if (t >= 589824) return;
    int tap = t / 65536, rem = t % 65536, ic = rem / 256, oc = rem % 256;
    wcv[t] = rpn_w[oc * 2304 + ic * 9 + tap];
}

// ---------------- feature pad: featP[ic][130][132], +1 halo of literal zeros -
__global__ void prep_pad(const float* __restrict__ feat, float* __restrict__ featP) {
    int t = blockIdx.x * 256 + threadIdx.x;
    if (t >= 256 * 130 * 132) return;
    int ic = t / 17160, rem = t % 17160, y = rem / 132, x = rem % 132;
    int sy = y - 1, sx = x - 1;
    float v = 0.f;
    if (sy >= 0 && sy < 128 && sx >= 0 && sx < 128)
        v = feat[ic * 16384 + sy * 128 + sx];
    featP[t] = v;
}

// ---------------- conv3x3: 8px x 4oc per thread, padded features -------------
// Bit-exact r12 chain per (px,oc): ONE f32 acc, k=(tap, ic 0..255) ascending.
__global__ __launch_bounds__(256, 2) void conv3x3(const float* __restrict__ featP,
                                                  const float* __restrict__ wcv,
                                                  const float* __restrict__ rpn_b,
                                                  float* __restrict__ xd) {
    __shared__ float sW[8192];                 // [ic][32 oc] for current tap
    const int band = blockIdx.x & 7;           // tile row (XCD-pinned)
    const int slot = blockIdx.x >> 3;          // 0..63
    const int tx = slot & 7, ocb = slot >> 3;  // tile col, oc-block(32)
    const int oc0 = ocb * 32;
    const int tid = threadIdx.x;
    const int ocg = tid >> 5;                  // 0..7 -> 4 oc each
    const int oct = tid & 31;
    const int py = oct >> 1, px0 = (oct & 1) * 8;
    const int gy = band * 16 + py, gx0 = tx * 16 + px0;
    const int ocB = oc0 + ocg * 4;
    float acc[8][4];
#pragma unroll
    for (int p = 0; p < 8; ++p)
#pragma unroll
        for (int o = 0; o < 4; ++o) acc[p][o] = 0.f;
#pragma unroll
    for (int tap = 0; tap < 9; ++tap) {        // k-major: tap (ky,kx)
        __syncthreads();
        for (int idx = tid; idx < 8192; idx += 256)
            sW[idx] = wcv[tap * 65536 + (idx >> 5) * 256 + oc0 + (idx & 31)];
        __syncthreads();
        const float* fp = featP + (size_t)(gy + tap / 3) * 132 + (gx0 + tap % 3);
        const float* wl = sW + ocg * 4;
        for (int ic = 0; ic < 256; ++ic) {     // k-minor: ic ascending
            const float* f8 = fp + (size_t)ic * 17160;
            float4a fA = *(const float4a*)(f8);
            float4a fB = *(const float4a*)(f8 + 4);
            float4a w4 = *(const float4a*)(wl + ic * 32);   // broadcast b128
#pragma unroll
            for (int p = 0; p < 4; ++p)
#pragma unroll
                for (int o = 0; o < 4; ++o)
                    acc[p][o] = __fmaf_rn(fA[p], w4[o], acc[p][o]);
#pragma unroll
            for (int p = 0; p < 4; ++p)
#pragma unroll
                for (int o = 0; o < 4; ++o)
                    acc[4 + p][o] = __fmaf_rn(fB[p], w4[o], acc[4 + p][o]);
        }
    }
#pragma unroll
    for (int p = 0; p < 8; ++p) {
        float* op = xd + (size_t)(gy * 128 + gx0 + p) * 256 + ocB;
#pragma unroll
        for (int o = 0; o < 4; ++o) {
            float v = __fadd_rn(acc[p][o], rpn_b[ocB + o]);
            op[o] = v > 0.f ? v : 0.f;
        }
    }
}

// ---------------- heads: 1x1 convs, k=ic sequential f32 FMA (float4 loads) ---
__global__ __launch_bounds__(256, 1) void heads_seq(const float* __restrict__ xd,
                                                    const float* __restrict__ cls_w,
                                                    const float* __restrict__ box_w,
                                                    float* __restrict__ dots) {
    __shared__ float sX[4][260];
    const int tid = threadIdx.x;
    const int pix0 = blockIdx.x * 4;
    for (int idx = tid; idx < 1024; idx += 256)
        sX[idx >> 8][idx & 255] = xd[(size_t)(pix0 + (idx >> 8)) * 256 + (idx & 255)];
    __syncthreads();
    if (tid < 216) {
        const int pl = tid / 54, o = tid % 54;
        const float* wr = (o < 18) ? (cls_w + o * 256) : (box_w + (o - 18) * 256);
        const float4* x4 = (const float4*)&sX[pl][0];
        const float4* w4 = (const float4*)wr;
        float acc = 0.f;
        for (int q = 0; q < 64; ++q) {
            float4 xv = x4[q];
            float4 wv = w4[q];
            acc = __fmaf_rn(xv.x, wv.x, acc);
            acc = __fmaf_rn(xv.y, wv.y, acc);
            acc = __fmaf_rn(xv.z, wv.z, acc);
            acc = __fmaf_rn(xv.w, wv.w, acc);
        }
        dots[(size_t)(pix0 + pl) * 54 + o] = acc;
    }
}

// ---------------- decode: stepwise-F32 softmax + box decode, XLA exp ---------
__global__ __launch_bounds__(256, 1) void decode(const float* __restrict__ dots,
                                                 const float* __restrict__ cls_b,
                                                 const float* __restrict__ box_b,
                                                 float4* __restrict__ boxes,
                                                 u64* __restrict__ keys) {
    const int pix = blockIdx.x * 256 + threadIdx.x;
    if (pix >= 16384) return;
    const float* dt = dots + (size_t)pix * 54;
    float d[54];
#pragma unroll
    for (int i = 0; i < 54; ++i)
        d[i] = __fadd_rn(dt[i], (i < 18 ? cls_b[i] : box_b[i - 18]));
    float m = d[0];
#pragma unroll
    for (int i = 1; i < 18; ++i) m = fmaxf(m, d[i]);
    float e[18];
#pragma unroll
    for (int i = 0; i < 18; ++i) e[i] = exp_xla(__fsub_rn(d[i], m));
    float s = e[0];
#pragma unroll
    for (int i = 1; i < 18; ++i) s = __fadd_rn(s, e[i]);
    const int y = pix >> 7, x = pix & 127;
    const float shx = (float)(x * 32), shy = (float)(y * 32);
    const float AW[9] = {368.f, 736.f, 1472.f, 256.f, 512.f, 1024.f, 176.f, 352.f, 704.f};
    const float AH[9] = {192.f, 384.f, 768.f, 256.f, 512.f, 1024.f, 352.f, 704.f, 1408.f};
#pragma unroll
    for (int a = 0; a < 9; ++a) {
        float score = e[9 + a] / s;
        float wa = AW[a], ha = AH[a];
        float cxa = __fadd_rn(shx, 7.5f), cya = __fadd_rn(shy, 7.5f);
        float dx = d[18 + 4 * a], dyy = d[19 + 4 * a];
        float dw = d[20 + 4 * a], dh = d[21 + 4 * a];
        float cx = __fadd_rn(__fmul_rn(dx, wa), cxa);
        float cy = __fadd_rn(__fmul_rn(dyy, ha), cya);
        float pw = __fmul_rn(wa, exp_xla(dw));
        float ph = __fmul_rn(ha, exp_xla(dh));
        float hx = __fmul_rn(0.5f, pw), hy = __fmul_rn(0.5f, ph);
        float x1 = fminf(fmaxf(__fsub_rn(cx, hx), 0.f), 4095.f);
        float y1 = fminf(fmaxf(__fsub_rn(cy, hy), 0.f), 4095.f);
        float x2 = fminf(fmaxf(__fadd_rn(cx, hx), 0.f), 4095.f);
        float y2 = fminf(fmaxf(__fadd_rn(cy, hy), 0.f), 4095.f);
        float vw = __fadd_rn(__fsub_rn(x2, x1), 1.0f);
        float vh = __fadd_rn(__fsub_rn(y2, y1), 1.0f);
        bool valid = (vw >= 16.0f) && (vh >= 16.0f);
        int i = pix * 9 + a;
        boxes[i] = make_float4(x1, y1, x2, y2);
        u64 k;
        if (valid) {
            u32 b = __float_as_uint(score);
            k = ((u64)(u32)~(b | 0x80000000u) << 32) | (u32)i;
        } else {
            k = (0xFFFFFFFFULL << 32) | (u32)i;
        }
        keys[i] = k;
    }
}

// ---------------- radix select: 8 passes of 8 bits, LDS histograms -----------
__global__ __launch_bounds__(256) void hist8(const u64* __restrict__ keys,
                                             u32* __restrict__ ghist,
                                             const u64* __restrict__ pfx, int pass) {
    __shared__ u32 lh[256];
    lh[threadIdx.x] = 0;
    __syncthreads();
    const u64 pref = *pfx;
    const int shift = 56 - 8 * pass;
    for (int i = blockIdx.x * 256 + threadIdx.x; i < 147456; i += 64 * 256) {
        u64 k = keys[i];
        bool match = (pass == 0) || ((k >> (shift + 8)) == pref);
        if (match) atomicAdd(&lh[(u32)(k >> shift) & 0xFFu], 1u);
    }
    __syncthreads();
    if (lh[threadIdx.x]) atomicAdd(&ghist[threadIdx.x], lh[threadIdx.x]);
}

__global__ __launch_bounds__(256) void scan8(const u32* __restrict__ ghist,
                                             u64* pfx, u32* tgt, int pass) {
    __shared__ u32 h[256];
    __shared__ u32 incl[256];
    const int t = threadIdx.x;
    u32 target = (pass == 0) ? 6000u : *tgt;
    u64 p0 = (pass == 0) ? 0ULL : *pfx;
    h[t] = ghist[t];
    incl[t] = h[t];
    __syncthreads();
    for (int off = 1; off < 256; off <<= 1) {
        u32 v = (t >= off) ? incl[t - off] : 0u;
        __syncthreads();
        incl[t] += v;
        __syncthreads();
    }
    u32 before = incl[t] - h[t];
    if (before < target && target <= incl[t]) {
        *pfx = (p0 << 8) | (u64)t;
        *tgt = target - before;
    }
}

__global__ void compact(const u64* __restrict__ keys, const u64* __restrict__ kstar,
                        u32* count, u64* __restrict__ ckey, u32* __restrict__ cidx) {
    int i = blockIdx.x * 256 + threadIdx.x;
    if (i >= 147456) return;
    u64 k = keys[i];
    if (k <= *kstar) {
        u32 pos = atomicAdd(count, 1u);
        if (pos < 6144) { ckey[pos] = k; cidx[pos] = (u32)(k & 0xFFFFFFFFu); }
    }
}

// ---------------- exact rank (keys unique) + gather sorted top-6000 ----------
__global__ __launch_bounds__(256) void rank_scatter(const u64* __restrict__ ckey,
                                                    const u32* __restrict__ cidx,
                                                    const u32* __restrict__ count,
                                                    const float4* __restrict__ boxes,
                                                    float4* __restrict__ tb,
                                                    float* __restrict__ tsc) {
    __shared__ u64 LK[6144];
    int N = (int)*count; if (N > 6144) N = 6144;
    for (int i = threadIdx.x; i < N; i += 256) LK[i] = ckey[i];
    __syncthreads();
    int e = blockIdx.x * 256 + threadIdx.x;
    if (e >= N) return;
    u64 myK = LK[e];
    u32 myI = cidx[e];
    int rank = 0;
    for (int c = 0; c < N; ++c) rank += (LK[c] < myK);
    if (rank < 6000) {
        tb[rank] = boxes[myI];
        u32 hi = (u32)(myK >> 32);
        tsc[rank] = (hi == 0xFFFFFFFFu) ? -__builtin_inff()
                                        : __uint_as_float(~hi & 0x7FFFFFFFu);
    }
}

// ---------------- alive bitmask init -----------------------------------------
__global__ void alive_init(const float* __restrict__ tsc, u64* __restrict__ alive0) {
    int r = blockIdx.x * 256 + threadIdx.x;
    bool a = false;
    if (r < 6000) a = tsc[r] > -__builtin_inff();
    u64 b = __ballot(a);
    if ((threadIdx.x & 63) == 0) alive0[r >> 6] = b;
}

// ---------------- suppression bitmask: m[j][i] = iou(tb[j],tb[i]) > 0.7 ------
__global__ __launch_bounds__(256) void nms_mask(const float4* __restrict__ tb,
                                                u64* __restrict__ mask) {
    int tid = blockIdx.x * 256 + threadIdx.x;
    if (tid >= 6000 * 94) return;
    int j = tid / 94, w = tid % 94;
    float4 bj = tb[j];
    float arJ = __fmul_rn(__fadd_rn(__fsub_rn(bj.z, bj.x), 1.0f),
                          __fadd_rn(__fsub_rn(bj.w, bj.y), 1.0f));
    u64 m = 0;
    int base = w * 64;
#pragma unroll 4
    for (int b = 0; b < 64; ++b) {
        int i = base + b;
        if (i >= 6000) break;
        float4 bi = tb[i];
        float arI = __fmul_rn(__fadd_rn(__fsub_rn(bi.z, bi.x), 1.0f),
                              __fadd_rn(__fsub_rn(bi.w, bi.y), 1.0f));
        float xx1 = fmaxf(bj.x, bi.x), yy1 = fmaxf(bj.y, bi.y);
        float xx2 = fminf(bj.z, bi.z), yy2 = fminf(bj.w, bi.w);
        float ww = fmaxf(__fadd_rn(__fsub_rn(xx2, xx1), 1.0f), 0.0f);
        float hh = fmaxf(__fadd_rn(__fsub_rn(yy2, yy1), 1.0f), 0.0f);
        float inter = __fmul_rn(ww, hh);
        float uni = __fsub_rn(__fadd_rn(arJ, arI), inter);
        float iou = inter / uni;
        if (iou > 0.7f) m |= (1ULL << b);
    }
    mask[(size_t)j * 96 + w] = m;
}

// ---------------- sequential NMS: register window, refill on miss ------------
// Selected j strictly increases; mask rows are static, so a register-cached
// window of rows [base, base+16) can serve multiple consecutive selections
// with ZERO memory traffic. Only on window overrun: direct row load + refill.
__global__ __launch_bounds__(64, 1) void nms_seq(const u64* __restrict__ alive0,
                                                 const u64* __restrict__ mask,
                                                 const float4* __restrict__ tb,
                                                 float* __restrict__ out) {
    const int lane = threadIdx.x;
    u64 wl = alive0[lane];
    u64 wh = (lane < 30) ? alive0[64 + lane] : 0ULL;
    u64 pl[16], ph[16];
    int base = 0;  // slots q hold row base+q
#pragma unroll
    for (int q = 0; q < 16; ++q) {
        pl[q] = mask[(size_t)q * 96 + lane];
        ph[q] = (lane < 30) ? mask[(size_t)q * 96 + 64 + lane] : 0ULL;
    }
    for (int k = 0; k < 1000; ++k) {
        // ---- j = first alive (strictly increasing across iterations) ----
        int j;
        {
            u64 blo = __ballot(wl != 0ULL);
            if (blo) {
                int l = __ffsll((long long)blo) - 1;
                u64 w = __shfl(wl, l);
                j = l * 64 + __ffsll((long long)w) - 1;
            } else {
                u64 bhi = __ballot(wh != 0ULL);
                if (!bhi) break;  // exhausted: remaining out rows stay 0
                int l = __ffsll((long long)bhi) - 1;
                u64 w = __shfl(wh, l);
                j = (64 + l) * 64 + __ffsll((long long)w) - 1;
            }
        }
        if (lane == 0) {
            float4 bj = tb[j];
            out[k * 5 + 1] = bj.x;
            out[k * 5 + 2] = bj.y;
            out[k * 5 + 3] = bj.z;
            out[k * 5 + 4] = bj.w;
        }
        // ---- row j: register window hit (no loads) or miss (load + refill) --
        const int s = j - base;
        u64 rl, rh;
        if (s >= 0 && s < 16) {
            rl = pl[0]; rh = ph[0];
#pragma unroll
            for (int q = 1; q < 16; ++q)
                if (s == q) { rl = pl[q]; rh = ph[q]; }
        } else {
            rl = mask[(size_t)j * 96 + lane];
            rh = (lane < 30) ? mask[(size_t)j * 96 + 64 + lane] : 0ULL;
            base = j + 1;  // refill window at j+1..j+16 (clamped)
#pragma unroll
            for (int q = 0; q < 16; ++q) {
                int r = base + q;
                if (r > 5999) r = 5999;
                pl[q] = mask[(size_t)r * 96 + lane];
                ph[q] = (lane < 30) ? mask[(size_t)r * 96 + 64 + lane] : 0ULL;
            }
        }
        // ---- apply row j (kills j itself via iou==1) ----
        wl &= ~rl;
        if (lane < 30) wh &= ~rh;
    }
}

// ---------------- host ----------------
extern "C" void kernel_launch(void* const* d_in, const int* in_sizes, int n_in,
                              void* d_out, int out_size, void* d_ws, size_t ws_size,
                              hipStream_t stream) {
    const float *feat = nullptr, *rpn_w = nullptr, *rpn_b = nullptr;
    const float *cls_w = nullptr, *cls_b = nullptr, *box_w = nullptr, *box_b = nullptr;
    for (int i = 0; i < n_in; ++i) {
        switch (in_sizes[i]) {
            case 4194304: feat  = (const float*)d_in[i]; break;
            case 589824:  rpn_w = (const float*)d_in[i]; break;
            case 256:     rpn_b = (const float*)d_in[i]; break;
            case 4608:    cls_w = (const float*)d_in[i]; break;
            case 18:      cls_b = (const float*)d_in[i]; break;
            case 9216:    box_w = (const float*)d_in[i]; break;
            case 36:      box_b = (const float*)d_in[i]; break;
            default: break;  // image dims hardcoded (4096)
        }
    }

    char* w = (char*)d_ws;
    u64* pfx       = (u64*)(w + OFF_CTL);
    u32* tgt       = (u32*)(w + OFF_CTL + 8);
    u32* ctlCount  = (u32*)(w + OFF_CTL + 12);
    u32* hist      = (u32*)(w + OFF_HIST);
    float* dots    = (float*)(w + OFF_DOTS);
    float* wcv     = (float*)(w + OFF_WCV);
    float* xd      = (float*)(w + OFF_XD);
    float4* boxes  = (float4*)(w + OFF_BOX);
    u64* keys      = (u64*)(w + OFF_KEYS);
    u64* ckey      = (u64*)(w + OFF_CKEY);
    u32* cidx      = (u32*)(w + OFF_CIDX);
    float4* tb     = (float4*)(w + OFF_TB);
    float* tsc     = (float*)(w + OFF_TSC);
    u64* alive0    = (u64*)(w + OFF_ALIVE);
    u64* mask      = (u64*)(w + OFF_MASK);
    float* featP   = (float*)(w + OFF_FPAD);

    hipMemsetAsync(d_ws, 0, OFF_HIST + 8 * 256 * 4, stream);  // ctl + 8 hists
    hipMemsetAsync(d_out, 0, (size_t)out_size * sizeof(float), stream);

    prep_wcv<<<2304, 256, 0, stream>>>(rpn_w, wcv);
    prep_pad<<<17160, 256, 0, stream>>>(feat, featP);
    conv3x3<<<512, 256, 0, stream>>>(featP, wcv, rpn_b, xd);
    heads_seq<<<4096, 256, 0, stream>>>(xd, cls_w, box_w, dots);
    decode<<<64, 256, 0, stream>>>(dots, cls_b, box_b, boxes, keys);
    for (int p = 0; p < 8; ++p) {
        hist8<<<64, 256, 0, stream>>>(keys, hist + p * 256, pfx, p);
        scan8<<<1, 256, 0, stream>>>(hist + p * 256, pfx, tgt, p);
    }
    compact<<<576, 256, 0, stream>>>(keys, pfx, ctlCount, ckey, cidx);
    rank_scatter<<<24, 256, 0, stream>>>(ckey, cidx, ctlCount, boxes, tb, tsc);
    alive_init<<<24, 256, 0, stream>>>(tsc, alive0);
    nms_mask<<<2204, 256, 0, stream>>>(tb, mask);
    nms_seq<<<1, 64, 0, stream>>>(alive0, mask, tb, (float*)d_out);
}